// Round 10
// baseline (137.162 us; speedup 1.0000x reference)
//
#include <hip/hip_runtime.h>
#include <hip/hip_bf16.h>

#define NPOS 6272          // 8*28*28
#define NT   98            // NPOS/64
#define CIN  256
#define CR   32
#define BATCH 2
// QSCALE * log2(e): scores come out in log2 units -> softmax uses raw exp2
#define QS2  0.25503371989518595f
#define PPITCH 136         // P^T LDS row pitch (shorts) for 128 keys: 272B

typedef short bf16x8s __attribute__((ext_vector_type(8)));  // 8 x 16b = 4 VGPR
typedef short short4v __attribute__((ext_vector_type(4)));  // 4 x 16b = 8B
typedef _Float16 f16x8 __attribute__((ext_vector_type(8))); // MFMA f16 A/B frag
typedef float f32x4   __attribute__((ext_vector_type(4)));
typedef unsigned short ushort_t;

__device__ __forceinline__ ushort_t f2bf(float f) {        // RNE fp32->bf16
    unsigned u = __builtin_bit_cast(unsigned, f);
    u += 0x7fff + ((u >> 16) & 1);
    return (ushort_t)(u >> 16);
}
__device__ __forceinline__ float bf2f(ushort_t h) {
    return __builtin_bit_cast(float, (unsigned)h << 16);
}
// fp32 -> fp16 bit pattern (compiler-lowered v_cvt_f16_f32, RNE)
__device__ __forceinline__ ushort_t f2h(float f) {
    return __builtin_bit_cast(ushort_t, (_Float16)f);
}

// ---------------------------------------------------------------------------
// Kernel 1: Q/K/V projections -> SINGLE fp16 arrays (R9-proven).
// grid (NT, B, 3); block 256 = 4 waves; wave g computes rows 8g..8g+7.
// ---------------------------------------------------------------------------
__global__ __launch_bounds__(256) void qkv_kernel(
    const float* __restrict__ x, const float* __restrict__ qw,
    const float* __restrict__ kw, const float* __restrict__ vw,
    ushort_t* __restrict__ Qf, ushort_t* __restrict__ Kf,
    ushort_t* __restrict__ Vt)
{
    const int b   = blockIdx.y;
    const int z   = blockIdx.z;
    const int nl  = threadIdx.x & 63;
    const int n   = blockIdx.x * 64 + nl;
    const int g   = __builtin_amdgcn_readfirstlane(threadIdx.x >> 6); // 0..3
    const float* w  = (z == 0) ? qw : (z == 1) ? kw : vw;
    const float* xb = x + (size_t)b * CIN * NPOS + n;

    float acc[8];
#pragma unroll
    for (int i = 0; i < 8; ++i) acc[i] = 0.f;
#pragma unroll 8
    for (int c = 0; c < CIN; ++c) {
        float xv = xb[(size_t)c * NPOS];
#pragma unroll
        for (int i = 0; i < 8; ++i)
            acc[i] += w[(g * 8 + i) * CIN + c] * xv;   // wave-uniform -> smem
    }
    if (z == 2) {                                // V -> transposed [32][N], f16
#pragma unroll
        for (int i = 0; i < 8; ++i)
            Vt[((size_t)b * CR + g * 8 + i) * NPOS + n] = f2h(acc[i]);
    } else {
        ushort_t* d = (z == 0) ? Qf : Kf;
        float s = (z == 0) ? QS2 : 1.0f;         // fold softmax scale into Q
        bf16x8s fh;
#pragma unroll
        for (int i = 0; i < 8; ++i)
            fh[i] = (short)f2h(acc[i] * s);
        *(bf16x8s*)(d + ((size_t)b * NPOS + n) * CR + g * 8) = fh;
    }
}

// ---------------------------------------------------------------------------
// Kernel 2: MFMA flash attention, TRANSPOSED scores (S^T = K·Q^T), fp16,
// R10: KVBLK = 128. R6's KVBLK=128 failed only from VGPR spills (hi/lo needed
// ~240 regs, capped at 128); fp16 halved the K footprint -> ~180 regs under
// the (128,2) 256 cap. Halves the per-wave serial-latency chains again
// (7 tiles/wave: shfl pairs, P LDS round-trips, prefetch batches) at equal
// total MFMA/LDS/bytes — the same mechanism that made R9's win.
// grid (98, S, B); block 128 = 2 independent waves (private pbuf halves).
// ---------------------------------------------------------------------------
__device__ __forceinline__ void load_k8(
    const ushort_t* __restrict__ Kfb, int j0, int col, int quad, bf16x8s* kf)
{
#pragma unroll
    for (int f = 0; f < 8; ++f)
        kf[f] = *(const bf16x8s*)(Kfb + (size_t)(j0 + f * 16 + col) * CR + quad * 8);
}
__device__ __forceinline__ void load_v8(
    const ushort_t* __restrict__ Vtb, int j0, int col, int quad, bf16x8s* vb)
{
#pragma unroll
    for (int k2 = 0; k2 < 4; ++k2)
#pragma unroll
        for (int c = 0; c < 2; ++c)
            vb[k2 * 2 + c] = *(const bf16x8s*)(
                Vtb + (size_t)(c * 16 + col) * NPOS + j0 + k2 * 32 + quad * 8);
}

__device__ __forceinline__ void compute_tile128(
    const bf16x8s* kf, const bf16x8s* vb, const bf16x8s* qb,
    f32x4 (&oc)[2][2], float (&m_)[2], float (&l_)[2],
    ushort_t* pb, int col, int quad)
{
    f32x4 z4 = {0.f, 0.f, 0.f, 0.f};
#pragma unroll
    for (int h = 0; h < 2; ++h) {
        f32x4 sc[8];                     // S^T: key = f*16+quad*4+r, q = col
#pragma unroll
        for (int f = 0; f < 8; ++f)
            sc[f] = __builtin_amdgcn_mfma_f32_16x16x32_f16(
                __builtin_bit_cast(f16x8, kf[f]),
                __builtin_bit_cast(f16x8, qb[h]), z4, 0, 0, 0);
        // 32 -> 1 max: per-frag max4 then max3 tree
        float mf[8];
#pragma unroll
        for (int f = 0; f < 8; ++f)
            mf[f] = fmaxf(fmaxf(sc[f][0], sc[f][1]), fmaxf(sc[f][2], sc[f][3]));
        float b0 = fmaxf(fmaxf(mf[0], mf[1]), mf[2]);
        float b1 = fmaxf(fmaxf(mf[3], mf[4]), mf[5]);
        float v  = fmaxf(fmaxf(b0, b1), fmaxf(mf[6], mf[7]));
        v = fmaxf(v, __shfl_xor(v, 16));
        v = fmaxf(v, __shfl_xor(v, 32));
        float mo = m_[h];
        float mn = mo;
        if (!__all(v <= mo)) {                   // max grew for some q: rescale
            mn = fmaxf(mo, v);
            float al = __builtin_amdgcn_exp2f(mo - mn);  // lane-uniform per q
            m_[h] = mn;
            l_[h] *= al;
#pragma unroll
            for (int r = 0; r < 4; ++r) { oc[h][0][r] *= al; oc[h][1][r] *= al; }
        }
        float lsum = 0.f;
#pragma unroll
        for (int f = 0; f < 8; ++f) {
            float p0 = __builtin_amdgcn_exp2f(sc[f][0] - mn);
            float p1 = __builtin_amdgcn_exp2f(sc[f][1] - mn);
            float p2 = __builtin_amdgcn_exp2f(sc[f][2] - mn);
            float p3 = __builtin_amdgcn_exp2f(sc[f][3] - mn);
            lsum += (p0 + p1) + (p2 + p3);
            short4v pk;
            pk[0] = (short)f2h(p0);
            pk[1] = (short)f2h(p1);
            pk[2] = (short)f2h(p2);
            pk[3] = (short)f2h(p3);
            *(short4v*)(&pb[h * 16 * PPITCH + col * PPITCH + f * 16 + quad * 4]) = pk;
        }
        l_[h] += lsum;
    }
    // PV: O^T += V^T · P^T (same-wave DS ops in-order; same-type LDS accesses
    // alias -> compiler preserves store->load order)
#pragma unroll
    for (int h = 0; h < 2; ++h) {
#pragma unroll
        for (int k2 = 0; k2 < 4; ++k2) {
            bf16x8s pbo = *(const bf16x8s*)(
                &pb[h * 16 * PPITCH + col * PPITCH + k2 * 32 + quad * 8]);
            oc[h][0] = __builtin_amdgcn_mfma_f32_16x16x32_f16(
                __builtin_bit_cast(f16x8, vb[k2 * 2 + 0]),
                __builtin_bit_cast(f16x8, pbo), oc[h][0], 0, 0, 0);
            oc[h][1] = __builtin_amdgcn_mfma_f32_16x16x32_f16(
                __builtin_bit_cast(f16x8, vb[k2 * 2 + 1]),
                __builtin_bit_cast(f16x8, pbo), oc[h][1], 0, 0, 0);
        }
    }
}

template <int ITERS>   // tiles of 128 keys per wave
__global__ __launch_bounds__(128, 2) void attn_kernel(
    const ushort_t* __restrict__ Qf, const ushort_t* __restrict__ Kf,
    const ushort_t* __restrict__ Vt, ushort_t* __restrict__ Opart,
    float* __restrict__ Mp, float* __restrict__ Lp)
{
    __shared__ __align__(16) ushort_t pbuf[2 * 2 * 16 * PPITCH];

    const int lane = threadIdx.x & 63;
    const int wv   = threadIdx.x >> 6;           // 0..1
    const int col  = lane & 15;                  // query (local)
    const int quad = lane >> 4;                  // 0..3
    const int b    = blockIdx.z;
    const int s    = blockIdx.y;
    const int qw0  = blockIdx.x * 64 + wv * 32;
    ushort_t* pb   = &pbuf[wv * 2 * 16 * PPITCH];

    const ushort_t* Qfb = Qf + (size_t)b * NPOS * CR;
    const ushort_t* Kfb = Kf + (size_t)b * NPOS * CR;
    const ushort_t* Vtb = Vt + (size_t)b * CR * NPOS;

    bf16x8s qb[2];                               // Q as B-operand (fp16 bits)
    qb[0] = *(const bf16x8s*)(Qfb + (size_t)(qw0 + col) * CR + quad * 8);
    qb[1] = *(const bf16x8s*)(Qfb + (size_t)(qw0 + 16 + col) * CR + quad * 8);

    f32x4 oc[2][2];
#pragma unroll
    for (int h = 0; h < 2; ++h)
#pragma unroll
        for (int c = 0; c < 2; ++c)
#pragma unroll
            for (int r = 0; r < 4; ++r) oc[h][c][r] = 0.f;
    float m_[2] = { -1e30f, -1e30f };
    float l_[2] = { 0.f, 0.f };

    const int base = s * ITERS;                  // in 128-key tiles

    if constexpr (ITERS <= 7) {
        // Full unroll; K parity double-buffer (compile-time indices -> SROA,
        // no rotation movs). V loaded per-tile (consumed late at PV).
        bf16x8s kf2[2][8];
        load_k8(Kfb, base * 128, col, quad, kf2[0]);
#pragma unroll
        for (int it = 0; it < ITERS; ++it) {
            const int cur = it & 1;
            bf16x8s vb[8];
            load_v8(Vtb, (base + it) * 128, col, quad, vb);
            if (it + 1 < ITERS)
                load_k8(Kfb, (base + it + 1) * 128, col, quad, kf2[cur ^ 1]);
            compute_tile128(kf2[cur], vb, qb, oc, m_, l_, pb, col, quad);
        }
    } else {                                     // fallback: plain rolled loop
#pragma unroll 1
        for (int it = 0; it < ITERS; ++it) {
            bf16x8s kf[8], vb[8];
            load_k8(Kfb, (base + it) * 128, col, quad, kf);
            load_v8(Vtb, (base + it) * 128, col, quad, vb);
            compute_tile128(kf, vb, qb, oc, m_, l_, pb, col, quad);
        }
    }

    // Finish l: reduce per-lane partials across quads (same q = same col).
#pragma unroll
    for (int h = 0; h < 2; ++h) {
        float l = l_[h];
        l += __shfl_xor(l, 16);
        l += __shfl_xor(l, 32);
        l_[h] = l;
    }

    const size_t sb = (size_t)(s * BATCH + b);
    ushort_t* Ob = Opart + sb * CR * NPOS;
#pragma unroll
    for (int h = 0; h < 2; ++h)
#pragma unroll
        for (int c = 0; c < 2; ++c)
#pragma unroll
            for (int r = 0; r < 4; ++r) {
                int ch = c * 16 + quad * 4 + r;
                Ob[(size_t)ch * NPOS + qw0 + h * 16 + col] = f2bf(oc[h][c][r]);
            }
    if (quad == 0) {                             // 16 lanes own the 16 q's
#pragma unroll
        for (int h = 0; h < 2; ++h) {
            Mp[sb * NPOS + qw0 + h * 16 + col] = m_[h];
            Lp[sb * NPOS + qw0 + h * 16 + col] = l_[h];
        }
    }
}

// ---------------------------------------------------------------------------
// Kernel 3: merge key-splits (log-sum-exp) -> Omrg [B][32][N] fp32.
// (R4-proven: Mp cached in registers) grid (NT, B, 8): wave g, ch r=z*4+g.
// ---------------------------------------------------------------------------
template <int S_>
__global__ __launch_bounds__(256) void merge_kernel(
    const ushort_t* __restrict__ Opart, const float* __restrict__ Mp,
    const float* __restrict__ Lp, float* __restrict__ Omrg)
{
    const int b  = blockIdx.y;
    const int z  = blockIdx.z;
    const int nl = threadIdx.x & 63;
    const int n  = blockIdx.x * 64 + nl;
    const int g  = __builtin_amdgcn_readfirstlane(threadIdx.x >> 6);
    const int r  = z * 4 + g;

    float mv[S_];
    float mg = -1e30f;
#pragma unroll
    for (int s = 0; s < S_; ++s) {
        mv[s] = Mp[(size_t)(s * BATCH + b) * NPOS + n];
        mg = fmaxf(mg, mv[s]);
    }
    float lg = 0.f, acc = 0.f;
#pragma unroll
    for (int s = 0; s < S_; ++s) {
        size_t sb = (size_t)(s * BATCH + b);
        float w = __builtin_amdgcn_exp2f(mv[s] - mg);
        lg  += w * Lp[sb * NPOS + n];
        acc += w * bf2f(Opart[(sb * CR + r) * NPOS + n]);   // coalesced
    }
    Omrg[((size_t)b * CR + r) * NPOS + n] = acc / lg;
}

// ---------------------------------------------------------------------------
// Kernel 4: output projection + residual (R4-proven version).
// grid (NT, B, 8), block 256: wave g handles 8 channels c in [z*32+8g, +8).
// ---------------------------------------------------------------------------
__global__ __launch_bounds__(256) void proj_kernel(
    const float* __restrict__ Omrg, const float* __restrict__ ow,
    const float* __restrict__ x, float* __restrict__ y)
{
    const int b  = blockIdx.y;
    const int z  = blockIdx.z;
    const int nl = threadIdx.x & 63;
    const int n  = blockIdx.x * 64 + nl;
    const int g  = __builtin_amdgcn_readfirstlane(threadIdx.x >> 6);

    float o[CR];
#pragma unroll
    for (int r = 0; r < CR; ++r)
        o[r] = Omrg[((size_t)b * CR + r) * NPOS + n];

    const float* xb = x + (size_t)b * CIN * NPOS + n;
    float*       yb = y + (size_t)b * CIN * NPOS + n;
    const int c0 = z * 32 + g * 8;
#pragma unroll
    for (int cc = 0; cc < 8; ++cc) {
        int c = c0 + cc;                          // wave-uniform
        float acc = xb[(size_t)c * NPOS];
#pragma unroll
        for (int r = 0; r < CR; ++r) acc += ow[c * CR + r] * o[r];
        yb[(size_t)c * NPOS] = acc;
    }
}

// ---------------------------------------------------------------------------
extern "C" void kernel_launch(void* const* d_in, const int* in_sizes, int n_in,
                              void* d_out, int out_size, void* d_ws, size_t ws_size,
                              hipStream_t stream)
{
    const float* x  = (const float*)d_in[0];
    const float* qw = (const float*)d_in[1];
    const float* kw = (const float*)d_in[2];
    const float* vw = (const float*)d_in[3];
    const float* ow = (const float*)d_in[4];
    float* out = (float*)d_out;

    const size_t qkvN = (size_t)BATCH * CR * NPOS;   // 401,408 elements
    // KVBLK=128 -> 49 tiles; S must divide 49: {7, 1}.
    const int s_cand[2] = {7, 1};
    int S = 1;
    for (int i = 0; i < 2; ++i) {
        int Sc = s_cand[i];
        size_t need = 3 * qkvN * sizeof(ushort_t)            // Qf,Kf,Vt
                    + qkvN * sizeof(float)                   // Omrg
                    + (size_t)Sc * qkvN * sizeof(ushort_t)   // Opart
                    + 2 * (size_t)Sc * BATCH * NPOS * sizeof(float); // M,L
        if (need <= ws_size) { S = Sc; break; }
    }
    ushort_t* Qf = (ushort_t*)d_ws;
    ushort_t* Kf = Qf + qkvN;
    ushort_t* Vt = Kf + qkvN;
    float* Omrg  = (float*)(Vt + qkvN);
    ushort_t* Op = (ushort_t*)(Omrg + qkvN);
    float* Mp    = (float*)(Op + (size_t)S * qkvN);
    float* Lp    = Mp + (size_t)S * BATCH * NPOS;

    qkv_kernel<<<dim3(NT, BATCH, 3), 256, 0, stream>>>(x, qw, kw, vw,
                                                       Qf, Kf, Vt);
    dim3 ag(NT, S, BATCH);
    if (S == 7)
        attn_kernel<7> <<<ag, 128, 0, stream>>>(Qf, Kf, Vt, Op, Mp, Lp);
    else
        attn_kernel<49><<<ag, 128, 0, stream>>>(Qf, Kf, Vt, Op, Mp, Lp);
    dim3 mg(NT, BATCH, 8);
    if (S == 7)
        merge_kernel<7><<<mg, 256, 0, stream>>>(Op, Mp, Lp, Omrg);
    else
        merge_kernel<1><<<mg, 256, 0, stream>>>(Op, Mp, Lp, Omrg);
    proj_kernel<<<dim3(NT, BATCH, 8), 256, 0, stream>>>(Omrg, ow, x, out);
}